// Round 6
// baseline (429.915 us; speedup 1.0000x reference)
//
#include <hip/hip_runtime.h>

#define BB 32
#define LL 4096
#define DD 512
#define NUM 32
#define KK 5
#define GRID 1024   // 4 blocks/CU on 256 CUs -> co-resident (cooperative)
#define GPB 32      // blocks per group (= per batch)
#define NGRP 32

typedef float f32x4 __attribute__((ext_vector_type(4)));

// lags = trunc(linspace(1, 168, 32)) -- precomputed, verified margins >= 0.03
__device__ __constant__ int d_LAGS[NUM] = {
    1, 6, 11, 17, 22, 27, 33, 38, 44, 49, 54, 60, 65, 71, 76, 81,
    87, 92, 97, 103, 108, 114, 119, 124, 130, 135, 141, 146, 151, 157, 162, 168};

// Zero the 96 group-barrier counters (3 barriers x 32 groups).
// d_ws is poisoned 0xAA before timing and never re-poisoned; the barrier must
// start from 0 every call, so this runs first in every kernel_launch.
__global__ __launch_bounds__(96) void k_init(int* __restrict__ ctrs) {
    ctrs[threadIdx.x] = 0;
}

// Group barrier among GPB co-resident blocks (cooperative launch guarantees
// residency). Device-scope fence + atomic: correct regardless of XCD mapping.
__device__ __forceinline__ void group_barrier(int* ctr) {
    __syncthreads();
    if (threadIdx.x == 0) {
        __threadfence();                 // release our group's writes
        atomicAdd(ctr, 1);
        while (__hip_atomic_load(ctr, __ATOMIC_ACQUIRE, __HIP_MEMORY_SCOPE_AGENT) < GPB) {
            __builtin_amdgcn_s_sleep(2);
        }
        __threadfence();                 // acquire other blocks' writes
    }
    __syncthreads();
}

// One kernel, 32 independent batch-pipelines. Group g (32 blocks, pinned to
// XCD g&7 by blockIdx round-robin heuristic) owns batch g:
//   mean -> bar -> scores -> bar -> topk -> bar -> combine.
// Phase math is bit-identical to the R5 4-kernel version.
__global__ __launch_bounds__(256, 4) void k_fused(const float* __restrict__ x,
                                                  float* __restrict__ xm,
                                                  float* __restrict__ scores,
                                                  float* __restrict__ wts,
                                                  int* __restrict__ sel,
                                                  float* __restrict__ out,
                                                  int* __restrict__ ctrs) {
    const int bid   = blockIdx.x;
    const int xcd   = bid & 7;
    const int slot  = bid >> 3;        // 0..127
    const int gi    = slot >> 5;       // 0..3
    const int rank  = slot & 31;       // 0..31 within group
    const int batch = xcd * 4 + gi;    // XCD owns 4 consecutive batches

    int* ctrA = ctrs + batch;
    int* ctrB = ctrs + NGRP + batch;
    int* ctrC = ctrs + 2 * NGRP + batch;

    const int tid  = threadIdx.x;
    const int wid  = tid >> 6;
    const int lane = tid & 63;

    // ---- Phase 1: row means for this batch (128 waves x 32 rows) ----
    {
        const int wv = rank * 4 + wid;                 // 0..127
        const float* xb = x + (size_t)batch * (LL * DD);
        float* xmb = xm + batch * LL;
        for (int i = 0; i < 32; ++i) {
            int row = wv * 32 + i;
            const float* p = xb + (size_t)row * DD;
            f32x4 a = *reinterpret_cast<const f32x4*>(p + 4 * lane);
            f32x4 b = *reinterpret_cast<const f32x4*>(p + 4 * lane + 256);
            float s = (a.x + a.y) + (a.z + a.w) + (b.x + b.y) + (b.z + b.w);
#pragma unroll
            for (int off = 32; off > 0; off >>= 1) s += __shfl_down(s, off, 64);
            if (lane == 0) xmb[row] = s * (1.0f / DD);
        }
    }
    group_barrier(ctrA);

    // ---- Phase 2: score for lag index 'rank' (same shape as proven k_scores) ----
    {
        int lag = d_LAGS[rank];
        const float* row = xm + batch * LL;
        int n = LL - lag;
        float s = 0.0f;
        for (int t = tid; t < n; t += 256) s += row[t] * row[t + lag];
#pragma unroll
        for (int off = 32; off > 0; off >>= 1) s += __shfl_down(s, off, 64);
        __shared__ float red[4];
        if (lane == 0) red[wid] = s;
        __syncthreads();
        if (tid == 0) {
            float tot = (red[0] + red[1]) + (red[2] + red[3]);
            scores[batch * NUM + rank] = tot / (float)n;
        }
    }
    group_barrier(ctrB);

    // ---- Phase 3: top-5 + weights (rank-0 block, thread 0) ----
    if (rank == 0 && tid == 0) {
        float v[NUM];
#pragma unroll
        for (int i = 0; i < NUM; i++) v[i] = scores[batch * NUM + i];
        float vals[KK];
        int   idx[KK];
#pragma unroll
        for (int j = 0; j < KK; j++) {
            float best = -INFINITY;
            int bi = 0;
#pragma unroll
            for (int i = 0; i < NUM; i++) {
                if (v[i] > best) { best = v[i]; bi = i; }
            }
            vals[j] = best;
            idx[j]  = bi;
            v[bi]   = -INFINITY;
        }
        float sum = 0.0f;
#pragma unroll
        for (int j = 0; j < KK; j++) sum += vals[j];
        float den = sum + 1e-6f;
#pragma unroll
        for (int j = 0; j < KK; j++) {
            wts[batch * KK + j] = vals[j] / den;
            sel[batch * KK + j] = d_LAGS[idx[j]];
        }
    }
    group_barrier(ctrC);

    // ---- Phase 4: combine. Group sweeps its batch's 2048 row-pairs in 64
    // lockstep-ish iterations (32 consecutive pairs/iter across the group),
    // preserving the sliding <=1.9 MB/XCD L2 window. NT stores keep x
    // L3-resident. ----
    {
        float ww[KK];
        int   lg[KK];
#pragma unroll
        for (int j = 0; j < KK; j++) {
            ww[j] = wts[batch * KK + j];
            lg[j] = sel[batch * KK + j];
        }
        const float* xb = x + (size_t)batch * (LL * DD);
        float* ob = out + (size_t)batch * (LL * DD);
        const int half = tid >> 7;     // 0..1
        const int d4   = tid & 127;
        for (int i = 0; i < 64; ++i) {
            int p  = i * 32 + rank;           // 0..2047
            int lt = p * 2 + half;            // local row 0..4095
            f32x4 acc = {0.f, 0.f, 0.f, 0.f};
#pragma unroll
            for (int j = 0; j < KK; j++) {
                int src = (lt - lg[j]) & (LL - 1);   // roll(+lag)
                f32x4 v = *reinterpret_cast<const f32x4*>(xb + (size_t)src * DD + 4 * d4);
                float wj = ww[j];
                acc.x += wj * v.x;
                acc.y += wj * v.y;
                acc.z += wj * v.z;
                acc.w += wj * v.w;
            }
            __builtin_nontemporal_store(acc,
                reinterpret_cast<f32x4*>(ob + (size_t)lt * DD + 4 * d4));
        }
    }
}

extern "C" void kernel_launch(void* const* d_in, const int* in_sizes, int n_in,
                              void* d_out, int out_size, void* d_ws, size_t ws_size,
                              hipStream_t stream) {
    const float* x = (const float*)d_in[0];
    float* out = (float*)d_out;

    char* ws = (char*)d_ws;
    int*   ctrs   = (int*)ws;                               // 96 ints
    float* xm     = (float*)(ws + 1024);                    // B*L floats = 512 KB
    float* scores = (float*)(ws + 1024 + (size_t)BB * LL * 4);
    float* wts    = (float*)(ws + 1024 + (size_t)BB * LL * 4 + BB * NUM * 4);
    int*   sel    = (int*)(ws + 1024 + (size_t)BB * LL * 4 + BB * NUM * 4 + BB * KK * 4);

    k_init<<<1, 96, 0, stream>>>(ctrs);

    void* args[] = {(void*)&x, (void*)&xm, (void*)&scores, (void*)&wts,
                    (void*)&sel, (void*)&out, (void*)&ctrs};
    hipLaunchCooperativeKernel((const void*)k_fused, dim3(GRID), dim3(256),
                               args, 0, stream);
}

// Round 7
// 266.002 us; speedup vs baseline: 1.6162x; 1.6162x over previous
//
#include <hip/hip_runtime.h>

#define BB 32
#define LL 4096
#define DD 512
#define NUM 32
#define KK 5
#define GRID 1024   // 4 blocks/CU on 256 CUs -> co-resident (cooperative)
#define GPB 32      // blocks per group (= per batch)
#define NGRP 32
#define CTR_STRIDE 64   // ints; 256 B per counter -> no false sharing (R6 lesson)
#define NCTR (2 * NGRP * CTR_STRIDE)   // 2 barriers x 32 groups, padded

typedef float f32x4 __attribute__((ext_vector_type(4)));

// lags = trunc(linspace(1, 168, 32)) -- precomputed, verified margins >= 0.03
__device__ __constant__ int d_LAGS[NUM] = {
    1, 6, 11, 17, 22, 27, 33, 38, 44, 49, 54, 60, 65, 71, 76, 81,
    87, 92, 97, 103, 108, 114, 119, 124, 130, 135, 141, 146, 151, 157, 162, 168};

// Zero the padded barrier counters. d_ws is poisoned 0xAA before timing and
// never re-poisoned; barriers must start from 0 on every call.
__global__ __launch_bounds__(256) void k_init(int* __restrict__ ctrs) {
    ctrs[blockIdx.x * 256 + threadIdx.x] = 0;
}

// Group barrier among GPB co-resident blocks (cooperative launch guarantees
// residency). Each group's counter sits on its own 256 B line: the R6 run's
// 478 us was cross-XCD ping-pong on ONE shared line for all 1024 blocks.
__device__ __forceinline__ void group_barrier(int* ctr) {
    __syncthreads();
    if (threadIdx.x == 0) {
        __threadfence();                 // release our group's writes
        atomicAdd(ctr, 1);
        while (__hip_atomic_load(ctr, __ATOMIC_ACQUIRE, __HIP_MEMORY_SCOPE_AGENT) < GPB) {
            __builtin_amdgcn_s_sleep(4);
        }
        __threadfence();                 // acquire other blocks' writes
    }
    __syncthreads();
}

// One kernel, 32 independent batch-pipelines. Group g (32 blocks) owns batch g:
//   mean -> bar -> scores -> bar -> (redundant per-block top5) -> combine.
// Phase math is bit-identical to the R5 4-kernel version.
__global__ __launch_bounds__(256, 4) void k_fused(const float* __restrict__ x,
                                                  float* __restrict__ xm,
                                                  float* __restrict__ scores,
                                                  float* __restrict__ out,
                                                  int* __restrict__ ctrs) {
    const int bid   = blockIdx.x;
    const int xcd   = bid & 7;
    const int slot  = bid >> 3;        // 0..127
    const int gi    = slot >> 5;       // 0..3
    const int rank  = slot & 31;       // 0..31 within group
    const int batch = xcd * 4 + gi;    // XCD owns 4 consecutive batches

    int* ctrA = ctrs + batch * CTR_STRIDE;
    int* ctrB = ctrs + (NGRP + batch) * CTR_STRIDE;

    const int tid  = threadIdx.x;
    const int wid  = tid >> 6;
    const int lane = tid & 63;

    // ---- Phase 1: row means for this batch (128 waves x 32 rows) ----
    {
        const int wv = rank * 4 + wid;                 // 0..127
        const float* xb = x + (size_t)batch * (LL * DD);
        float* xmb = xm + batch * LL;
        for (int i = 0; i < 32; ++i) {
            int row = wv * 32 + i;
            const float* p = xb + (size_t)row * DD;
            f32x4 a = *reinterpret_cast<const f32x4*>(p + 4 * lane);
            f32x4 b = *reinterpret_cast<const f32x4*>(p + 4 * lane + 256);
            float s = (a.x + a.y) + (a.z + a.w) + (b.x + b.y) + (b.z + b.w);
#pragma unroll
            for (int off = 32; off > 0; off >>= 1) s += __shfl_down(s, off, 64);
            if (lane == 0) xmb[row] = s * (1.0f / DD);
        }
    }
    group_barrier(ctrA);

    // ---- Phase 2: score for lag index 'rank' (proven k_scores shape) ----
    {
        int lag = d_LAGS[rank];
        const float* row = xm + batch * LL;
        int n = LL - lag;
        float s = 0.0f;
        for (int t = tid; t < n; t += 256) s += row[t] * row[t + lag];
#pragma unroll
        for (int off = 32; off > 0; off >>= 1) s += __shfl_down(s, off, 64);
        __shared__ float red[4];
        if (lane == 0) red[wid] = s;
        __syncthreads();
        if (tid == 0) {
            float tot = (red[0] + red[1]) + (red[2] + red[3]);
            scores[batch * NUM + rank] = tot / (float)n;
        }
    }
    group_barrier(ctrB);

    // ---- Phase 3: top-5 + weights, redundantly per block (deterministic ->
    // identical in every block; removes the third barrier + serial phase) ----
    __shared__ float ww_s[KK];
    __shared__ int   lg_s[KK];
    if (tid == 0) {
        float v[NUM];
#pragma unroll
        for (int i = 0; i < NUM; i++) v[i] = scores[batch * NUM + i];
        float vals[KK];
        int   idx[KK];
#pragma unroll
        for (int j = 0; j < KK; j++) {
            float best = -INFINITY;
            int bi = 0;
#pragma unroll
            for (int i = 0; i < NUM; i++) {
                if (v[i] > best) { best = v[i]; bi = i; }
            }
            vals[j] = best;
            idx[j]  = bi;
            v[bi]   = -INFINITY;
        }
        float sum = 0.0f;
#pragma unroll
        for (int j = 0; j < KK; j++) sum += vals[j];
        float den = sum + 1e-6f;
#pragma unroll
        for (int j = 0; j < KK; j++) {
            ww_s[j] = vals[j] / den;
            lg_s[j] = d_LAGS[idx[j]];
        }
    }
    __syncthreads();

    // ---- Phase 4: combine. Group sweeps its batch's 2048 row-pairs in 64
    // iterations (32 consecutive pairs/iter across the group): sliding
    // <=1.9 MB/XCD window stays L2-hot. NT stores keep x L3-resident. ----
    {
        float ww[KK];
        int   lg[KK];
#pragma unroll
        for (int j = 0; j < KK; j++) {
            ww[j] = ww_s[j];
            lg[j] = lg_s[j];
        }
        const float* xb = x + (size_t)batch * (LL * DD);
        float* ob = out + (size_t)batch * (LL * DD);
        const int half = tid >> 7;     // 0..1
        const int d4   = tid & 127;
        for (int i = 0; i < 64; ++i) {
            int p  = i * 32 + rank;           // 0..2047
            int lt = p * 2 + half;            // local row 0..4095
            f32x4 acc = {0.f, 0.f, 0.f, 0.f};
#pragma unroll
            for (int j = 0; j < KK; j++) {
                int src = (lt - lg[j]) & (LL - 1);   // roll(+lag)
                f32x4 v = *reinterpret_cast<const f32x4*>(xb + (size_t)src * DD + 4 * d4);
                float wj = ww[j];
                acc.x += wj * v.x;
                acc.y += wj * v.y;
                acc.z += wj * v.z;
                acc.w += wj * v.w;
            }
            __builtin_nontemporal_store(acc,
                reinterpret_cast<f32x4*>(ob + (size_t)lt * DD + 4 * d4));
        }
    }
}

extern "C" void kernel_launch(void* const* d_in, const int* in_sizes, int n_in,
                              void* d_out, int out_size, void* d_ws, size_t ws_size,
                              hipStream_t stream) {
    const float* x = (const float*)d_in[0];
    float* out = (float*)d_out;

    char* ws = (char*)d_ws;
    int*   ctrs   = (int*)ws;                               // NCTR ints = 16 KB
    float* xm     = (float*)(ws + NCTR * 4);                // B*L floats = 512 KB
    float* scores = (float*)(ws + NCTR * 4 + (size_t)BB * LL * 4);

    k_init<<<NCTR / 256, 256, 0, stream>>>(ctrs);

    void* args[] = {(void*)&x, (void*)&xm, (void*)&scores, (void*)&out, (void*)&ctrs};
    hipLaunchCooperativeKernel((const void*)k_fused, dim3(GRID), dim3(256),
                               args, 0, stream);
}